// Round 7
// baseline (226.763 us; speedup 1.0000x reference)
//
#include <hip/hip_runtime.h>

// GlobalAttentionPooling: tensor_square_0e -> selu -> @W -> segment softmax -> weighted segment sum
// N nodes, 80 f32 ft (32 scalar + 16 x 3-vec), NG=1024 graphs (sorted batch_index), F=664.
//
// Math identities (validated rounds 1-6, absmax 3.9e-3):
//   selu const term cancels in softmax; pre-scale s by sqrt(log2e), v by sqrt(log2e/sqrt3)
//   so pair products are f*log2e -> exp2 directly. out_g = (sum nf*ex)/z_g.
//
// Round-7 diagnosis: VGPR_Count=36 across r5/r6 with no spill stores + 40-60MB excess FETCH
// => the machine scheduler (occupancy-maximizing) SINKS row loads to uses, re-reading
// operands from L1/L2 all through the triangle -> L2-latency-bound at ~90us regardless of
// source structure. Fix: amdgpu_waves_per_eu(2,3) aligns the scheduler's occupancy target
// with the grid-limited reality (~2.3 waves/SIMD), freeing ~170 VGPRs so the row stays
// register-resident. 2 nodes/thread (node-pair f2, r2's proven codegen) for in-wave ILP;
// W via uniform s_load with literal offsets; hot loop has ZERO per-iteration VMEM/DS ops.

typedef float f2 __attribute__((ext_vector_type(2)));

#define C0 32
#define C1 16
#define NODE_F 80
#define NG_CONST 1024
#define NPB 320                 // threads per block; block owns 640 nodes
#define NODES_PB 640

#define SELU_SCALE 1.0507009873554804934193349852946
#define SELU_ALPHA 1.6732632423543772848170429916717
#define LOG2E      1.4426950408889634073599246810019

#define CS_SCALE 1.2011224087864498f    // sqrt(log2e)
#define CV_SCALE 0.91271231102878545f   // sqrt(log2e/sqrt(3))

// ws float layout: [0, 81920) S accum [1024][80]; [81920, 82944) z accum [1024]
#define WS_S 0
#define WS_Z 81920

// zero the global accumulators
__global__ __launch_bounds__(256) void prep_kernel(float* __restrict__ ws)
{
    const int t = blockIdx.x * blockDim.x + threadIdx.x;
    if (t < 82944) ws[t] = 0.0f;
}

__global__ __launch_bounds__(NPB)
__attribute__((amdgpu_waves_per_eu(2, 3)))
void main_kernel(
    const float* __restrict__ nf, const int* __restrict__ bi,
    const float* __restrict__ W, float* __restrict__ S,
    float* __restrict__ z, int N)
{
    __shared__ float exl[NODES_PB];
    __shared__ int   bil[NODES_PB];

    const int tid  = threadIdx.x;
    const int base = blockIdx.x * NODES_PB;
    const float4* g4 = (const float4*)nf;

    // two node streams, both lane-adjacent (coalesced): na = base+tid, nb = na+320
    const int  na = base + tid;
    const int  nb = na + NPB;
    const bool va = (na < N), vb = (nb < N);
    const int  ea = va ? na : (N - 1);
    const int  eb = vb ? nb : (N - 1);
    bil[tid]       = bi[ea];
    bil[tid + NPB] = bi[eb];

    const float4* rpa = g4 + (size_t)ea * 20;
    const float4* rpb = g4 + (size_t)eb * 20;

    f2 accA[2], accB[2];
    accA[0] = (f2)0.f; accA[1] = (f2)0.f; accB[0] = (f2)0.f; accB[1] = (f2)0.f;
    int k = 0;

    // ---------- phase S: 32 scalar channels, 528 triu pairs (node-pair f2) ----------
    {
        f2 s2[C0];
        #pragma unroll
        for (int q = 0; q < 8; ++q) {
            float4 A = rpa[q], B = rpb[q];
            s2[4 * q + 0] = f2{A.x, B.x} * CS_SCALE;
            s2[4 * q + 1] = f2{A.y, B.y} * CS_SCALE;
            s2[4 * q + 2] = f2{A.z, B.z} * CS_SCALE;
            s2[4 * q + 3] = f2{A.w, B.w} * CS_SCALE;
        }
        #pragma unroll
        for (int i = 0; i < C0; ++i) {
            #pragma unroll
            for (int j = i; j < C0; ++j) {
                f2 f = s2[i] * s2[j];                  // {fA, fB} * log2e
                f2 p = __builtin_elementwise_max(f, (f2)0.f);
                f2 m = __builtin_elementwise_min(f, (f2)0.f);
                f2 e; e.x = __builtin_amdgcn_exp2f(m.x);
                      e.y = __builtin_amdgcn_exp2f(m.y);
                const float w = W[k]; ++k;             // uniform -> merged s_load
                accA[j & 1] = __builtin_elementwise_fma((f2)w, p, accA[j & 1]);
                accB[j & 1] = __builtin_elementwise_fma((f2)w, e, accB[j & 1]);
            }
        }
    }
    // ---------- phase V: 16 3-vec channels, 136 triu dot pairs ----------
    {
        f2 vs2[3 * C1];
        #pragma unroll
        for (int q = 0; q < 12; ++q) {
            float4 A = rpa[8 + q], B = rpb[8 + q];
            vs2[4 * q + 0] = f2{A.x, B.x} * CV_SCALE;
            vs2[4 * q + 1] = f2{A.y, B.y} * CV_SCALE;
            vs2[4 * q + 2] = f2{A.z, B.z} * CV_SCALE;
            vs2[4 * q + 3] = f2{A.w, B.w} * CV_SCALE;
        }
        #pragma unroll
        for (int i = 0; i < C1; ++i) {
            #pragma unroll
            for (int j = i; j < C1; ++j) {
                f2 f = vs2[3 * i] * vs2[3 * j];
                f = __builtin_elementwise_fma(vs2[3 * i + 1], vs2[3 * j + 1], f);
                f = __builtin_elementwise_fma(vs2[3 * i + 2], vs2[3 * j + 2], f);
                f2 p = __builtin_elementwise_max(f, (f2)0.f);
                f2 m = __builtin_elementwise_min(f, (f2)0.f);
                f2 e; e.x = __builtin_amdgcn_exp2f(m.x);
                      e.y = __builtin_amdgcn_exp2f(m.y);
                const float w = W[k]; ++k;
                accA[j & 1] = __builtin_elementwise_fma((f2)w, p, accA[j & 1]);
                accB[j & 1] = __builtin_elementwise_fma((f2)w, e, accB[j & 1]);
            }
        }
    }

    f2 A1 = accA[0] + accA[1];
    f2 A2 = accB[0] + accB[1];
    f2 l2 = A1 * (float)SELU_SCALE;
    l2 = __builtin_elementwise_fma((f2)(float)(SELU_SCALE * SELU_ALPHA * LOG2E), A2, l2);
    exl[tid]       = va ? __builtin_amdgcn_exp2f(l2.x) : 0.0f;
    exl[tid + NPB] = vb ? __builtin_amdgcn_exp2f(l2.y) : 0.0f;
    __syncthreads();

    // ---- phase 2: thread (no, c4) sums 40 contiguous nodes' channel-group, flush per graph run ----
    const int no = tid / 20;       // 0..15
    const int c4 = tid % 20;
    int cg = bil[no * 40];
    float4 acc = make_float4(0.f, 0.f, 0.f, 0.f);
    float  zacc = 0.0f;

    #pragma unroll 4
    for (int kk = 0; kk < 40; ++kk) {
        const int nl = no * 40 + kk;
        const int g2 = bil[nl];
        if (g2 != cg) {
            unsafeAtomicAdd(&S[cg * NODE_F + c4 * 4 + 0], acc.x);
            unsafeAtomicAdd(&S[cg * NODE_F + c4 * 4 + 1], acc.y);
            unsafeAtomicAdd(&S[cg * NODE_F + c4 * 4 + 2], acc.z);
            unsafeAtomicAdd(&S[cg * NODE_F + c4 * 4 + 3], acc.w);
            if (c4 == 0) unsafeAtomicAdd(&z[cg], zacc);
            acc = make_float4(0.f, 0.f, 0.f, 0.f); zacc = 0.0f; cg = g2;
        }
        int idx = base + nl; if (idx > N - 1) idx = N - 1;   // pad nodes have w=0
        const float  w = exl[nl];
        const float4 v = g4[(size_t)idx * 20 + c4];
        acc.x = fmaf(v.x, w, acc.x); acc.y = fmaf(v.y, w, acc.y);
        acc.z = fmaf(v.z, w, acc.z); acc.w = fmaf(v.w, w, acc.w);
        zacc += w;
    }
    unsafeAtomicAdd(&S[cg * NODE_F + c4 * 4 + 0], acc.x);
    unsafeAtomicAdd(&S[cg * NODE_F + c4 * 4 + 1], acc.y);
    unsafeAtomicAdd(&S[cg * NODE_F + c4 * 4 + 2], acc.z);
    unsafeAtomicAdd(&S[cg * NODE_F + c4 * 4 + 3], acc.w);
    if (c4 == 0) unsafeAtomicAdd(&z[cg], zacc);
}

__global__ __launch_bounds__(256) void divide_kernel(
    const float* __restrict__ S, const float* __restrict__ z,
    float* __restrict__ out)
{
    const int t = blockIdx.x * blockDim.x + threadIdx.x;
    if (t >= NG_CONST * NODE_F) return;
    const float zz = z[t / NODE_F];
    out[t] = (zz > 0.0f) ? (S[t] / zz) : 0.0f;
}

extern "C" void kernel_launch(void* const* d_in, const int* in_sizes, int n_in,
                              void* d_out, int out_size, void* d_ws, size_t ws_size,
                              hipStream_t stream) {
    const float* nf = (const float*)d_in[0];   // (N, 80) f32
    const int*   bi = (const int*)d_in[1];     // (N,) i32 sorted
    // d_in[2] = num_graphs (static 1024)
    const float* W  = (const float*)d_in[3];   // (664,) f32
    float* out = (float*)d_out;

    const int N = in_sizes[0] / NODE_F;
    float* ws = (float*)d_ws;
    float* S  = ws + WS_S;
    float* z  = ws + WS_Z;

    hipLaunchKernelGGL(prep_kernel, dim3(324), dim3(256), 0, stream, ws);
    hipLaunchKernelGGL(main_kernel, dim3((N + NODES_PB - 1) / NODES_PB), dim3(NPB),
                       0, stream, nf, bi, W, S, z, N);
    hipLaunchKernelGGL(divide_kernel, dim3((NG_CONST * NODE_F + 255) / 256), dim3(256),
                       0, stream, S, z, out);
}